// Round 12
// baseline (111.010 us; speedup 1.0000x reference)
//
#include <hip/hip_runtime.h>
#include <stdint.h>

typedef _Float16 half8  __attribute__((ext_vector_type(8)));
typedef float    floatx4 __attribute__((ext_vector_type(4)));
typedef uint32_t uint4v  __attribute__((ext_vector_type(4)));

#define KDIM 4096
#define ODIM 11008
#define NG   32

__device__ __forceinline__ uint32_t pk_f16(float a, float b) {
    return __builtin_bit_cast(uint32_t, __builtin_amdgcn_cvt_pkrtz(a, b));
}

// x fp32 [64][4096] -> f16 fragments xh2[g][ks][mt][lane] (uint4, halves
// slot-paired (x_j, x_{j+4})) + per-(group,m) row sums xsumT[32][64].
// chunk c of row m: g=c>>4, q=(c&15)>>2, ks=c&3, mt=m>>4, ml=m&15, lane=q*16+ml.
// (layout HW-verified in rounds 10/11, absmax 0.125)
__global__ __launch_bounds__(256) void cvt_x_kernel(
    const float4* __restrict__ x, uint4v* __restrict__ xh2,
    float* __restrict__ xsumT)
{
    const int i = blockIdx.x * 256 + threadIdx.x;   // chunk id 0..32767
    const float4 f0 = x[2 * i];
    const float4 f1 = x[2 * i + 1];
    const uint4v v = {pk_f16(f0.x, f1.x), pk_f16(f0.y, f1.y),
                      pk_f16(f0.z, f1.z), pk_f16(f0.w, f1.w)};
    const int m  = i >> 9, c = i & 511;
    const int g  = c >> 4, cg = c & 15, q = cg >> 2, ks = cg & 3;
    const int mt = m >> 4, ml = m & 15;
    xh2[((size_t)(g * 4 + ks) * 4 + mt) * 64 + q * 16 + ml] = v;

    float p = f0.x + f0.y + f0.z + f0.w + f1.x + f1.y + f1.z + f1.w;
    p += __shfl_xor(p, 1);
    p += __shfl_xor(p, 2);
    p += __shfl_xor(p, 4);
    p += __shfl_xor(p, 8);
    if ((threadIdx.x & 15) == 0) xsumT[g * 64 + m] = p;
}

// Block: 16 o-cols x FULL K. 4 waves = 4 k-quarters (8 groups each), each wave
// covers all 64 m (4 M-tiles). qweight unique per wave (1 uint4/lane/group,
// 1-deep register prefetch, NO LDS staging, NO main-loop barriers). Final
// combine: one LDS reduce across waves + direct stores (no partials/atomics).
// Grid: 688 blocks. Zero-point via rowsum correction folded into acc.
__global__ __launch_bounds__(256, 4) void w4a16_kernel(
    const uint4v*   __restrict__ xh2,    // [32][4][4][64] uint4
    const uint4v*   __restrict__ qw,     // [11008][128] uint4
    const uint32_t* __restrict__ qz,     // [11008][4]
    const float*    __restrict__ sc,     // [11008][32] (fp32-upcast fp16)
    const float*    __restrict__ xsumT,  // [32][64]
    float*          __restrict__ out)    // [64][11008]
{
    __shared__ float red[4][16][64];     // 16 KB

    const int t    = threadIdx.x;
    const int kw   = t >> 6;            // wave -> k-quarter (groups kw*8..+7)
    const int lane = t & 63;
    const int q    = lane >> 4;
    const int ml   = lane & 15;

    const int o0 = blockIdx.x * 16;
    const int o  = o0 + ml;             // B col = ml
    const int g0 = kw * 8;

    const uint4v* qwp = qw + (size_t)o * 128 + g0 * 4 + q;
    const uint32_t zdw = qz[(size_t)o * 4 + kw];      // 8 nibbles = our 8 groups
    const floatx4 sv0 = *reinterpret_cast<const floatx4*>(sc + (size_t)o * NG + g0);
    const floatx4 sv1 = *reinterpret_cast<const floatx4*>(sc + (size_t)o * NG + g0 + 4);

    const uint4v* xp = xh2 + (size_t)g0 * 1024 + lane;       // + (gl*16+ks*4+mt)*64
    const float*  xs = xsumT + (size_t)g0 * 64 + q * 4;      // + gl*64 + mt*16

    floatx4 acc[4] = {{0.f,0.f,0.f,0.f},{0.f,0.f,0.f,0.f},
                      {0.f,0.f,0.f,0.f},{0.f,0.f,0.f,0.f}};

    uint4v ucur = qwp[0];

    #pragma unroll
    for (int gl = 0; gl < 8; ++gl) {
        uint4v unext;
        if (gl + 1 < 8) unext = qwp[(gl + 1) * 4];

        const uint32_t zn  = (zdw >> (gl * 4)) & 0xFu;
        const float    s   = (gl < 4) ? sv0[gl] : sv1[gl - 4];
        const float    czs = s * (1024.0f + (float)zn);

        floatx4 tmp[4] = {{0.f,0.f,0.f,0.f},{0.f,0.f,0.f,0.f},
                          {0.f,0.f,0.f,0.f},{0.f,0.f,0.f,0.f}};
        #pragma unroll
        for (int ks = 0; ks < 4; ++ks) {
            // A fragments for 4 M-tiles (independent MFMA chains across mt)
            uint4v ax[4];
            #pragma unroll
            for (int mt = 0; mt < 4; ++mt)
                ax[mt] = xp[(size_t)(gl * 16 + ks * 4 + mt) * 64];

            const uint32_t ud = ucur[ks];
            const uint4v bw = {
                ( ud         & 0x000F000Fu) | 0x64006400u,
                ((ud >> 4)   & 0x000F000Fu) | 0x64006400u,
                ((ud >> 8)   & 0x000F000Fu) | 0x64006400u,
                ((ud >> 12)  & 0x000F000Fu) | 0x64006400u};
            const half8 b = __builtin_bit_cast(half8, bw);
            #pragma unroll
            for (int mt = 0; mt < 4; ++mt)
                tmp[mt] = __builtin_amdgcn_mfma_f32_16x16x32_f16(
                    __builtin_bit_cast(half8, ax[mt]), b, tmp[mt], 0, 0, 0);
        }

        // scale + zero-point correction (rowsums from L1-resident xsumT)
        #pragma unroll
        for (int mt = 0; mt < 4; ++mt) {
            const floatx4 xg = *reinterpret_cast<const floatx4*>(
                xs + gl * 64 + mt * 16);
            #pragma unroll
            for (int r = 0; r < 4; ++r)
                acc[mt][r] += s * tmp[mt][r] - czs * xg[r];
        }
        ucur = unext;
    }

    // cross-wave k-reduce through LDS, then direct final stores
    #pragma unroll
    for (int mt = 0; mt < 4; ++mt)
        #pragma unroll
        for (int r = 0; r < 4; ++r)
            red[kw][mt * 4 + r][lane] = acc[mt][r];
    __syncthreads();

    const int mt2 = t >> 6;             // reuse wave id as output M-tile
    #pragma unroll
    for (int r = 0; r < 4; ++r) {
        const int i = mt2 * 4 + r;
        const float sum = red[0][i][lane] + red[1][i][lane]
                        + red[2][i][lane] + red[3][i][lane];
        out[(size_t)(mt2 * 16 + q * 4 + r) * ODIM + o] = sum;
    }
}

extern "C" void kernel_launch(void* const* d_in, const int* in_sizes, int n_in,
                              void* d_out, int out_size, void* d_ws, size_t ws_size,
                              hipStream_t stream) {
    const float*    x       = (const float*)d_in[0];
    const uint32_t* qweight = (const uint32_t*)d_in[1];
    const uint32_t* qzeros  = (const uint32_t*)d_in[2];
    const float*    scales  = (const float*)d_in[3];
    float* out = (float*)d_out;

    uint4v* xh2   = (uint4v*)d_ws;                         // 512 KB
    float*  xsumT = (float*)((char*)d_ws + 512 * 1024);    // 8 KB

    cvt_x_kernel<<<dim3(128), dim3(256), 0, stream>>>((const float4*)x, xh2, xsumT);
    w4a16_kernel<<<dim3(ODIM / 16), dim3(256), 0, stream>>>(
        xh2, (const uint4v*)qweight, qzeros, scales, xsumT, out);
}